// Round 13
// baseline (4984.978 us; speedup 1.0000x reference)
//
#include <hip/hip_runtime.h>
#include <stdint.h>

#define H_DIM   1024
#define G3      3072
#define EMB     50
#define TSTEPS  100
#define NB      4096
#define NLABEL  15

typedef __bf16 bf16x8 __attribute__((ext_vector_type(8)));
typedef float  f32x4  __attribute__((ext_vector_type(4)));
typedef int    i32x4  __attribute__((ext_vector_type(4)));

__device__ inline uint16_t f2bf(float f) {
  uint32_t u = __builtin_bit_cast(uint32_t, f);
  u += 0x7FFFu + ((u >> 16) & 1u);   // round-to-nearest-even
  return (uint16_t)(u >> 16);
}

__device__ inline void gld16(const void* g, void* l) {
  __builtin_amdgcn_global_load_lds(
      (const __attribute__((address_space(1))) uint32_t*)g,
      (__attribute__((address_space(3))) uint32_t*)l, 16, 0, 0);
}

// counted vmcnt + sched fence (rule #18: MFMA can hoist past bare asm waits)
#define VM(n) do { asm volatile("s_waitcnt vmcnt(" #n ")" ::: "memory"); \
                   __builtin_amdgcn_sched_barrier(0); } while (0)
#define LGKM0() do { asm volatile("s_waitcnt lgkmcnt(0)" ::: "memory"); \
                     __builtin_amdgcn_sched_barrier(0); } while (0)
#define BARF() do { __builtin_amdgcn_s_barrier(); \
                    asm volatile("" ::: "memory"); } while (0)
// async global->reg 16B load at immediate byte offset
#define GLDB(dst, addr, OFF) \
  asm volatile("global_load_dwordx4 %0, %1, off offset:" OFF \
               : "=&v"(dst) : "v"(addr) : "memory")

// ---------------- prep kernels (unchanged from r9) ----------------

__global__ __launch_bounds__(256) void prep_recT(const float* __restrict__ rec,
                                                 uint16_t* __restrict__ recT) {
  __shared__ uint16_t st[64][72];
  const int n0 = blockIdx.x * 64;
  const int k0 = blockIdx.y * 64;
  const int tid = threadIdx.x;
#pragma unroll
  for (int i = 0; i < 16; ++i) {
    int idx = tid + i * 256;
    int r = idx >> 6;
    int c = idx & 63;
    st[c][r] = f2bf(rec[(size_t)(k0 + r) * G3 + n0 + c]);
  }
  __syncthreads();
#pragma unroll
  for (int i = 0; i < 16; ++i) {
    int idx = tid + i * 256;
    int r = idx >> 6;
    int c = idx & 63;
    recT[(size_t)(n0 + r) * H_DIM + k0 + c] = st[r][c];
  }
}

__global__ __launch_bounds__(256) void prep_kerT(const float* __restrict__ ker,
                                                 uint16_t* __restrict__ kerT) {
  int n = blockIdx.x * 4 + (threadIdx.x >> 6);
  int k = threadIdx.x & 63;
  float v = (k < EMB) ? ker[(size_t)k * G3 + n] : 0.f;
  kerT[(size_t)n * 64 + k] = f2bf(v);
}

// Bpk[colblk16][kt17][g3][wn2][nf2][ks2][lane64][e8] bf16 — MFMA-fragment
// order: per wave, gate g = 4 contiguous 1KB chunks at byte offsets
// 0/1024/2048/3072. kt=16 = input-projection tile (from kerT).
__global__ __launch_bounds__(256) void prep_pack(const uint16_t* __restrict__ recT,
                                                 const uint16_t* __restrict__ kerT,
                                                 uint16_t* __restrict__ Bpk) {
  int cid = blockIdx.x * 256 + threadIdx.x;   // 16B chunk id (417792 total)
  int lane = cid & 63;
  int r = cid >> 6;
  int ks = r & 1; r >>= 1;
  int nf = r & 1; r >>= 1;
  int wn = r & 1; r >>= 1;
  int g  = r % 3; r /= 3;
  int kt = r % 17;
  int colblk = r / 17;
  int n  = g * H_DIM + colblk * 64 + wn * 32 + nf * 16 + (lane & 15);
  int kk = ks * 32 + (lane >> 4) * 8;
  const uint16_t* src = (kt < 16) ? recT + (size_t)n * H_DIM + kt * 64 + kk
                                  : kerT + (size_t)n * 64 + kk;
  *reinterpret_cast<i32x4*>(Bpk + (size_t)cid * 8) =
      *reinterpret_cast<const i32x4*>(src);
}

__global__ __launch_bounds__(256) void prep_embt(const int* __restrict__ x,
                                                 const float* __restrict__ tab,
                                                 uint16_t* __restrict__ embt) {
  int idx = blockIdx.x * 256 + threadIdx.x;
  int g = idx >> 5;
  int p = idx & 31;
  int t = g >> 12;
  int b = g & 4095;
  int row = x[b * TSTEPS + t];
  float2 v;
  if (p < 25) v = *reinterpret_cast<const float2*>(tab + (size_t)row * EMB + 2 * p);
  else { v.x = 0.f; v.y = 0.f; }
  uint32_t packed = (uint32_t)f2bf(v.x) | ((uint32_t)f2bf(v.y) << 16);
  *reinterpret_cast<uint32_t*>(embt + (size_t)g * 64 + 2 * p) = packed;
}

// ---------------- fused GRU step ----------------
// grid 512 (2 blocks/CU), block 256 (4 waves, 2x2). Tile: 128 rows x 64 cols,
// 3 gates. DEEP PIPELINE vs r9: B 2-tiles-deep in regs (bfvA/bfvB, B(t+2)
// issued at tile t), A 3-buffer LDS rotation (A(t+3) issued at tile t).
// Steady tile = {stageA, 3x(MFG+ISSUE), readA, LGKM0, VM(16), BARF} — no
// waits before MFMA (B(t) landed via previous tile's VM(16)); 16-32 loads
// outstanding per wave at all times.
__global__ __launch_bounds__(256, 2) void gru_step_kernel(
    const uint16_t* __restrict__ hb_prev,   // [4096][1024] bf16
    float* __restrict__ hf,                 // [4096][1024] f32 (in-place)
    uint16_t* __restrict__ hb_next,         // [4096][1024] bf16
    const uint16_t* __restrict__ Bpk,       // packed B (see prep_pack)
    const uint16_t* __restrict__ embt,      // [4096][64]   bf16 (this step)
    const float* __restrict__ bias_i,       // [3072]
    const float* __restrict__ bias_r) {     // [3072]
  __shared__ __align__(16) uint16_t sA[3][128 * 64];      // 48 KB

  const int tid  = threadIdx.x;
  const int lane = tid & 63;
  const int wid  = tid >> 6;     // 0..3
  const int wm   = wid >> 1;     // wave row 0..1 (64 rows each)
  const int wn   = wid & 1;      // wave col 0..1 (32 cols each)
  const int bid  = blockIdx.x;
  // XCD remap: xk = bid%8 -> XCD; each XCD: 8 rowblks x 8 colblks
  const int xk = bid & 7, slot = bid >> 3;          // slot 0..63
  const int rowblk = (xk >> 1) * 8 + (slot >> 3);   // 0..31
  const int colblk = (xk & 1) * 8 + (slot & 7);     // 0..15
  const int r0 = rowblk * 128;
  const int j0 = colblk * 64;

  const int swz8 = 8 * ((lane & 7) ^ (lane >> 3));

  bf16x8 af[4][2];                  // A-frags (single-buffered)
  i32x4  bfvA[3][2][2], bfvB[3][2][2];   // B-frags, 2-tile double buffer
  f32x4 accZ[4][2], accR[4][2], accH[4][2], accX[4][2];
#pragma unroll
  for (int m = 0; m < 4; ++m)
#pragma unroll
    for (int n = 0; n < 2; ++n) {
      accZ[m][n] = (f32x4){0.f, 0.f, 0.f, 0.f};
      accR[m][n] = (f32x4){0.f, 0.f, 0.f, 0.f};
      accH[m][n] = (f32x4){0.f, 0.f, 0.f, 0.f};
      accX[m][n] = (f32x4){0.f, 0.f, 0.f, 0.f};
    }

  // Packed-B wave pointers, one per gate; advance 24576 B per K-tile.
  // elem strides: kt=12288, g=4096, wn=2048, nf=1024, ks=512, lane=8.
  const uint16_t* pB[3];
#pragma unroll
  for (int g = 0; g < 3; ++g)
    pB[g] = Bpk + (size_t)colblk * 17 * 12288 + g * 4096 + wn * 2048 + lane * 8;

  // stage A-tile for tile t into sA[t%3] (4 gld16/thread, 16 KB)
  auto stageA = [&](int t) {
    int ab = t % 3;
#pragma unroll
    for (int i = 0; i < 4; ++i) {
      int chunk = wid * 4 + i;                // 0..15
      int row = chunk * 8 + (lane >> 3);
      const uint16_t* src = (t < 16)
          ? hb_prev + (size_t)(r0 + row) * H_DIM + t * 64 + swz8
          : embt + (size_t)(r0 + row) * 64 + swz8;
      gld16(src, &sA[ab][(chunk * 64 + lane) * 8]);
    }
  };
  // read A fragments for tile t (8 ds_read_b128)
  auto readA = [&](int t) {
    int ab = t % 3;
#pragma unroll
    for (int ks = 0; ks < 2; ++ks) {
      const int colswz = (ks * 32 + (lane >> 4) * 8) ^ ((lane & 7) << 3);
#pragma unroll
      for (int mf = 0; mf < 4; ++mf)
        af[mf][ks] = *reinterpret_cast<const bf16x8*>(
            &sA[ab][(wm * 64 + mf * 16 + (lane & 15)) * 64 + colswz]);
    }
  };

// issue 4 coalesced 1KB B-loads of gate g into BF (FIFO: nf0ks0..nf1ks1)
#define ISSUE_BG(g, BF) do { \
    GLDB(BF[g][0][0], pB[g], "0");    GLDB(BF[g][0][1], pB[g], "1024"); \
    GLDB(BF[g][1][0], pB[g], "2048"); GLDB(BF[g][1][1], pB[g], "3072"); \
  } while (0)
// 16 MFMA of gate g from BF into ACC
#define MFG(g, BF, ACC) do { \
    __builtin_amdgcn_s_setprio(1); \
    _Pragma("unroll") for (int ks = 0; ks < 2; ++ks) \
    _Pragma("unroll") for (int nf = 0; nf < 2; ++nf) \
    _Pragma("unroll") for (int mf = 0; mf < 4; ++mf) \
      ACC[mf][nf] = __builtin_amdgcn_mfma_f32_16x16x32_bf16( \
          af[mf][ks], __builtin_bit_cast(bf16x8, BF[g][nf][ks]), \
          ACC[mf][nf], 0, 0, 0); \
    __builtin_amdgcn_s_setprio(0); \
  } while (0)
#define ADV_B() do { _Pragma("unroll") \
    for (int g = 0; g < 3; ++g) pB[g] += 12288; } while (0)

// steady tile: no waits before MFMA (B(t) landed by prior tile's VM(16));
// issue A(t+3) and B(t+2); single drain leaves [A(t+3)4, B(t+2)12].
#define TILE_STEADY(t, BF) do { \
    stageA((t) + 3); \
    MFG(0, BF, accZ); ISSUE_BG(0, BF); \
    MFG(1, BF, accR); ISSUE_BG(1, BF); \
    MFG(2, BF, accH); ISSUE_BG(2, BF); ADV_B(); \
    readA((t) + 1); LGKM0(); \
    VM(16); BARF(); \
  } while (0)

  // -------- prologue: A(0..2) staged; B(0)->bfvA, B(1)->bfvB issued --------
  stageA(0); stageA(1); stageA(2);
  ISSUE_BG(0, bfvA); ISSUE_BG(1, bfvA); ISSUE_BG(2, bfvA); ADV_B();  // kt=1
  ISSUE_BG(0, bfvB); ISSUE_BG(1, bfvB); ISSUE_BG(2, bfvB); ADV_B();  // kt=2
  VM(12);                        // A(0..2)+B(0) landed; B(1) x12 in flight
  BARF();
  readA(0);

  // -------- steady tiles 0..13 (2-unrolled for static bfv parity) ----------
  for (int tt = 0; tt < 14; tt += 2) {
    TILE_STEADY(tt, bfvA);
    TILE_STEADY(tt + 1, bfvB);
  }

  // -------- tile 14 (even->bfvA; last B issue kt=16; no stageA) ------------
  MFG(0, bfvA, accZ); ISSUE_BG(0, bfvA);
  MFG(1, bfvA, accR); ISSUE_BG(1, bfvA);
  MFG(2, bfvA, accH); ISSUE_BG(2, bfvA);
  readA(15); LGKM0();
  VM(12);                        // drain A(16)+B(15); leave [B(16) x12]
  BARF();
  // -------- tile 15 (odd->bfvB; nothing to issue) --------------------------
  MFG(0, bfvB, accZ);
  MFG(1, bfvB, accR);
  MFG(2, bfvB, accH);
  readA(16); LGKM0();
  VM(0);                         // B(16) landed
  // -------- tile 16 (even->bfvA = input projection; gate-2 -> accX) --------
  MFG(0, bfvA, accZ);
  MFG(1, bfvA, accR);
  MFG(2, bfvA, accX);

#undef ISSUE_BG
#undef MFG
#undef ADV_B
#undef TILE_STEADY

  // -------- epilogue: gates in fp32, write h (f32 master + bf16) --------
#pragma unroll
  for (int nf = 0; nf < 2; ++nf) {
    int col = j0 + wn * 32 + nf * 16 + (lane & 15);
    float b_z = bias_i[col] + bias_r[col];
    float b_r = bias_i[H_DIM + col] + bias_r[H_DIM + col];
    float bih = bias_i[2 * H_DIM + col];
    float brh = bias_r[2 * H_DIM + col];
#pragma unroll
    for (int mf = 0; mf < 4; ++mf) {
#pragma unroll
      for (int q = 0; q < 4; ++q) {
        int row = r0 + wm * 64 + mf * 16 + (lane >> 4) * 4 + q;
        float z  = 1.f / (1.f + __expf(-(accZ[mf][nf][q] + b_z)));
        float rr = 1.f / (1.f + __expf(-(accR[mf][nf][q] + b_r)));
        float pre = accX[mf][nf][q] + bih + rr * (accH[mf][nf][q] + brh);
        float hc  = 2.f / (1.f + __expf(-2.f * pre)) - 1.f;   // tanh
        size_t idx = (size_t)row * H_DIM + col;
        float hold = hf[idx];
        float hnew = z * hold + (1.f - z) * hc;
        hf[idx] = hnew;
        hb_next[idx] = f2bf(hnew);
      }
    }
  }
}

// ---------------- final logits ----------------
__global__ __launch_bounds__(64) void logits_kernel(const float* __restrict__ hf,
                                                    const float* __restrict__ Wd,
                                                    const float* __restrict__ bd,
                                                    float* __restrict__ out) {
  int b = blockIdx.x;
  int l = threadIdx.x;
  float p[NLABEL];
#pragma unroll
  for (int o = 0; o < NLABEL; ++o) p[o] = 0.f;
  for (int kb = 0; kb < 16; ++kb) {
    int k = kb * 64 + l;
    float hv = hf[(size_t)b * H_DIM + k];
#pragma unroll
    for (int o = 0; o < NLABEL; ++o) p[o] += hv * Wd[k * NLABEL + o];
  }
#pragma unroll
  for (int o = 0; o < NLABEL; ++o) {
#pragma unroll
    for (int s = 32; s; s >>= 1) p[o] += __shfl_xor(p[o], s);
  }
  if (l == 0) {
#pragma unroll
    for (int o = 0; o < NLABEL; ++o) out[(size_t)b * NLABEL + o] = p[o] + bd[o];
  }
}

// ---------------- launch ----------------
extern "C" void kernel_launch(void* const* d_in, const int* in_sizes, int n_in,
                              void* d_out, int out_size, void* d_ws, size_t ws_size,
                              hipStream_t stream) {
  const int*   x          = (const int*)d_in[0];
  // d_in[1] = drop_rate (static 0, ignored)
  const float* emb_table  = (const float*)d_in[2];
  const float* kernel_w   = (const float*)d_in[3];
  const float* rec_kernel = (const float*)d_in[4];
  const float* bias_i     = (const float*)d_in[5];
  const float* bias_r     = (const float*)d_in[6];
  const float* Wd         = (const float*)d_in[7];
  const float* bd         = (const float*)d_in[8];
  float* out = (float*)d_out;

  char* ws = (char*)d_ws;
  size_t off = 0;
  auto alloc = [&](size_t bytes) {
    char* p = ws + off;
    off += (bytes + 255) & ~(size_t)255;
    return p;
  };
  float*    hf   = (float*)alloc((size_t)NB * H_DIM * 4);
  uint16_t* hb0  = (uint16_t*)alloc((size_t)NB * H_DIM * 2);
  uint16_t* hb1  = (uint16_t*)alloc((size_t)NB * H_DIM * 2);
  uint16_t* recT = (uint16_t*)alloc((size_t)G3 * H_DIM * 2);
  uint16_t* kerT = (uint16_t*)alloc((size_t)G3 * 64 * 2);
  uint16_t* embt = (uint16_t*)alloc((size_t)TSTEPS * NB * 64 * 2);
  uint16_t* Bpk  = (uint16_t*)alloc((size_t)16 * 17 * 12288 * 2);
  if (off > ws_size) return;  // insufficient workspace -> fail loudly

  hipMemsetAsync(hf, 0, (size_t)NB * H_DIM * 4, stream);
  hipMemsetAsync(hb0, 0, (size_t)NB * H_DIM * 2, stream);

  prep_recT<<<dim3(G3 / 64, H_DIM / 64), 256, 0, stream>>>(rec_kernel, recT);
  prep_kerT<<<G3 / 4, 256, 0, stream>>>(kernel_w, kerT);
  prep_pack<<<1632, 256, 0, stream>>>(recT, kerT, Bpk);
  prep_embt<<<TSTEPS * NB * 32 / 256, 256, 0, stream>>>(x, emb_table, embt);

  uint16_t* hb[2] = {hb0, hb1};
  for (int t = 0; t < TSTEPS; ++t) {
    gru_step_kernel<<<512, 256, 0, stream>>>(
        hb[t & 1], hf, hb[(t + 1) & 1], Bpk,
        embt + (size_t)t * NB * 64, bias_i, bias_r);
  }
  logits_kernel<<<NB, 64, 0, stream>>>(hf, Wd, bd, out);
}

// Round 14
// 3133.665 us; speedup vs baseline: 1.5908x; 1.5908x over previous
//
#include <hip/hip_runtime.h>
#include <stdint.h>

#define H_DIM   1024
#define G3      3072
#define EMB     50
#define TSTEPS  100
#define NB      4096
#define NLABEL  15

typedef __bf16 bf16x8 __attribute__((ext_vector_type(8)));
typedef float  f32x4  __attribute__((ext_vector_type(4)));
typedef int    i32x4  __attribute__((ext_vector_type(4)));

__device__ inline uint16_t f2bf(float f) {
  uint32_t u = __builtin_bit_cast(uint32_t, f);
  u += 0x7FFFu + ((u >> 16) & 1u);   // round-to-nearest-even
  return (uint16_t)(u >> 16);
}

__device__ inline void gld16(const void* g, void* l) {
  __builtin_amdgcn_global_load_lds(
      (const __attribute__((address_space(1))) uint32_t*)g,
      (__attribute__((address_space(3))) uint32_t*)l, 16, 0, 0);
}

// counted vmcnt + sched fence (rule #18: MFMA can hoist past bare asm waits)
#define VM(n) do { asm volatile("s_waitcnt vmcnt(" #n ")" ::: "memory"); \
                   __builtin_amdgcn_sched_barrier(0); } while (0)
#define LGKM0() do { asm volatile("s_waitcnt lgkmcnt(0)" ::: "memory"); \
                     __builtin_amdgcn_sched_barrier(0); } while (0)
#define BARF() do { __builtin_amdgcn_s_barrier(); \
                    asm volatile("" ::: "memory"); } while (0)

// ---------------- prep kernels (unchanged from r9) ----------------

__global__ __launch_bounds__(256) void prep_recT(const float* __restrict__ rec,
                                                 uint16_t* __restrict__ recT) {
  __shared__ uint16_t st[64][72];
  const int n0 = blockIdx.x * 64;
  const int k0 = blockIdx.y * 64;
  const int tid = threadIdx.x;
#pragma unroll
  for (int i = 0; i < 16; ++i) {
    int idx = tid + i * 256;
    int r = idx >> 6;
    int c = idx & 63;
    st[c][r] = f2bf(rec[(size_t)(k0 + r) * G3 + n0 + c]);
  }
  __syncthreads();
#pragma unroll
  for (int i = 0; i < 16; ++i) {
    int idx = tid + i * 256;
    int r = idx >> 6;
    int c = idx & 63;
    recT[(size_t)(n0 + r) * H_DIM + k0 + c] = st[r][c];
  }
}

__global__ __launch_bounds__(256) void prep_kerT(const float* __restrict__ ker,
                                                 uint16_t* __restrict__ kerT) {
  int n = blockIdx.x * 4 + (threadIdx.x >> 6);
  int k = threadIdx.x & 63;
  float v = (k < EMB) ? ker[(size_t)k * G3 + n] : 0.f;
  kerT[(size_t)n * 64 + k] = f2bf(v);
}

// Bpk[colblk16][kt17][g3][wn2][nf2][ks2][lane64][e8] bf16 — MFMA-fragment
// order. kt=16 = input-projection tile (from kerT). A block's tile slice is
// one contiguous 24576B region.
__global__ __launch_bounds__(256) void prep_pack(const uint16_t* __restrict__ recT,
                                                 const uint16_t* __restrict__ kerT,
                                                 uint16_t* __restrict__ Bpk) {
  int cid = blockIdx.x * 256 + threadIdx.x;   // 16B chunk id (417792 total)
  int lane = cid & 63;
  int r = cid >> 6;
  int ks = r & 1; r >>= 1;
  int nf = r & 1; r >>= 1;
  int wn = r & 1; r >>= 1;
  int g  = r % 3; r /= 3;
  int kt = r % 17;
  int colblk = r / 17;
  int n  = g * H_DIM + colblk * 64 + wn * 32 + nf * 16 + (lane & 15);
  int kk = ks * 32 + (lane >> 4) * 8;
  const uint16_t* src = (kt < 16) ? recT + (size_t)n * H_DIM + kt * 64 + kk
                                  : kerT + (size_t)n * 64 + kk;
  *reinterpret_cast<i32x4*>(Bpk + (size_t)cid * 8) =
      *reinterpret_cast<const i32x4*>(src);
}

__global__ __launch_bounds__(256) void prep_embt(const int* __restrict__ x,
                                                 const float* __restrict__ tab,
                                                 uint16_t* __restrict__ embt) {
  int idx = blockIdx.x * 256 + threadIdx.x;
  int g = idx >> 5;
  int p = idx & 31;
  int t = g >> 12;
  int b = g & 4095;
  int row = x[b * TSTEPS + t];
  float2 v;
  if (p < 25) v = *reinterpret_cast<const float2*>(tab + (size_t)row * EMB + 2 * p);
  else { v.x = 0.f; v.y = 0.f; }
  uint32_t packed = (uint32_t)f2bf(v.x) | ((uint32_t)f2bf(v.y) << 16);
  *reinterpret_cast<uint32_t*>(embt + (size_t)g * 64 + 2 * p) = packed;
}

// ---------------- fused GRU step ----------------
// grid 512 (2 blocks/CU), block 256 (4 waves, 2x2). Tile: 128 rows x 64 cols,
// 3 gates. NEW vs r9: B staged ONCE per block into LDS via gld16 (packed Bpk
// linear copy, 24.6KB/tile, double-buffered) — halves VMEM requests; B-frag
// ds_read is contiguous lane*16 (conflict-free). LDS = 32+48 = 80KB exactly
// (2 blocks/CU). 2 barriers + one VM(10) per tile; 2 tiles of staging in
// flight; vmcnt never 0 until the tail.
__global__ __launch_bounds__(256, 2) void gru_step_kernel(
    const uint16_t* __restrict__ hb_prev,   // [4096][1024] bf16
    float* __restrict__ hf,                 // [4096][1024] f32 (in-place)
    uint16_t* __restrict__ hb_next,         // [4096][1024] bf16
    const uint16_t* __restrict__ Bpk,       // packed B (see prep_pack)
    const uint16_t* __restrict__ embt,      // [4096][64]   bf16 (this step)
    const float* __restrict__ bias_i,       // [3072]
    const float* __restrict__ bias_r) {     // [3072]
  __shared__ __align__(16) uint16_t sA2[2][128 * 64];     // 32 KB
  __shared__ __align__(16) uint16_t sB2[2][12288];        // 48 KB

  const int tid  = threadIdx.x;
  const int lane = tid & 63;
  const int wid  = tid >> 6;     // 0..3
  const int wm   = wid >> 1;     // wave row 0..1 (64 rows each)
  const int wn   = wid & 1;      // wave col 0..1 (32 cols each)
  const int bid  = blockIdx.x;
  // XCD remap: xk = bid%8 -> XCD; each XCD: 8 rowblks x 8 colblks
  const int xk = bid & 7, slot = bid >> 3;          // slot 0..63
  const int rowblk = (xk >> 1) * 8 + (slot >> 3);   // 0..31
  const int colblk = (xk & 1) * 8 + (slot & 7);     // 0..15
  const int r0 = rowblk * 128;
  const int j0 = colblk * 64;

  const int swz8 = 8 * ((lane & 7) ^ (lane >> 3));

  const uint16_t* pBcol = Bpk + (size_t)colblk * 17 * 12288;

  bf16x8 af[4][2];               // A-frags (single-buffered)
  bf16x8 bfr[3][2][2];           // B-frags [gate][nf][ks] (single-buffered)
  f32x4 accZ[4][2], accR[4][2], accH[4][2], accX[4][2];
#pragma unroll
  for (int m = 0; m < 4; ++m)
#pragma unroll
    for (int n = 0; n < 2; ++n) {
      accZ[m][n] = (f32x4){0.f, 0.f, 0.f, 0.f};
      accR[m][n] = (f32x4){0.f, 0.f, 0.f, 0.f};
      accH[m][n] = (f32x4){0.f, 0.f, 0.f, 0.f};
      accX[m][n] = (f32x4){0.f, 0.f, 0.f, 0.f};
    }

  // stage A-tile for tile t (4 gld16/thread, 16 KB)
  auto stageA = [&](int t) {
    const int abuf = t & 1;
#pragma unroll
    for (int i = 0; i < 4; ++i) {
      int chunk = wid * 4 + i;                // 0..15
      int row = chunk * 8 + (lane >> 3);
      const uint16_t* src = (t < 16)
          ? hb_prev + (size_t)(r0 + row) * H_DIM + t * 64 + swz8
          : embt + (size_t)(r0 + row) * 64 + swz8;
      gld16(src, &sA2[abuf][(chunk * 64 + lane) * 8]);
    }
  };
  // stage B-tile for tile t: linear copy of the packed 24576B region
  // (6 gld16/thread). LDS dest = wave-uniform base + lane*16 (linear). ✓
  auto stageB = [&](int t) {
    const int bbuf = t & 1;
    const uint16_t* base = pBcol + (size_t)t * 12288;
#pragma unroll
    for (int i = 0; i < 6; ++i) {
      int e = (i * 256 + tid) * 8;            // element offset
      gld16(base + e, &sB2[bbuf][e]);
    }
  };
  // read A fragments for tile t (8 ds_read_b128, swizzled)
  auto readA = [&](int t) {
    const int abuf = t & 1;
#pragma unroll
    for (int ks = 0; ks < 2; ++ks) {
      const int colswz = (ks * 32 + (lane >> 4) * 8) ^ ((lane & 7) << 3);
#pragma unroll
      for (int mf = 0; mf < 4; ++mf)
        af[mf][ks] = *reinterpret_cast<const bf16x8*>(
            &sA2[abuf][(wm * 64 + mf * 16 + (lane & 15)) * 64 + colswz]);
    }
  };
  // read B fragments for tile t (12 ds_read_b128, contiguous lane*16)
  auto readB = [&](int t) {
    const int bbuf = t & 1;
#pragma unroll
    for (int g = 0; g < 3; ++g)
#pragma unroll
      for (int nf = 0; nf < 2; ++nf)
#pragma unroll
        for (int ks = 0; ks < 2; ++ks) {
          int c = g * 8 + wn * 4 + nf * 2 + ks;   // packed chunk index
          bfr[g][nf][ks] = *reinterpret_cast<const bf16x8*>(
              &sB2[bbuf][c * 512 + lane * 8]);
        }
  };

// 16 MFMA of gate g into ACC
#define MFG(g, ACC) do { \
    __builtin_amdgcn_s_setprio(1); \
    _Pragma("unroll") for (int ks = 0; ks < 2; ++ks) \
    _Pragma("unroll") for (int nf = 0; nf < 2; ++nf) \
    _Pragma("unroll") for (int mf = 0; mf < 4; ++mf) \
      ACC[mf][nf] = __builtin_amdgcn_mfma_f32_16x16x32_bf16( \
          af[mf][ks], bfr[g][nf][ks], ACC[mf][nf], 0, 0, 0); \
    __builtin_amdgcn_s_setprio(0); \
  } while (0)

  // -------- prologue: stage tiles 0,1 (10 items each); read frags(0) -------
  stageA(0); stageB(0);
  stageA(1); stageB(1);
  VM(10);                        // S(0) landed; S(1) x10 in flight
  BARF();
  readA(0); readB(0);
  LGKM0();

  // -------- steady tiles 0..14 --------------------------------------------
  // invariant at loop top: frags(t) in regs; outstanding = [S(t+1) x10]
  for (int t = 0; t < 15; ++t) {
    BARF();                      // barrier-a: all threads done reading buf t%2
    stageA(t + 2); stageB(t + 2);        // overwrite buf t%2
    MFG(0, accZ);
    MFG(1, accR);
    MFG(2, accH);
    VM(10);                      // S(t+1) landed (mine); leave [S(t+2) x10]
    BARF();                      // barrier-b: S(t+1) landed for all
    readA(t + 1); readB(t + 1);  // frags for next tile
    LGKM0();
  }

  // -------- tile 15 (frags in regs; nothing to stage) ----------------------
  MFG(0, accZ);
  MFG(1, accR);
  MFG(2, accH);
  VM(0);                         // S(16) landed
  BARF();
  readA(16); readB(16);
  LGKM0();
  // -------- tile 16 (input projection; gate-2 -> accX) ---------------------
  MFG(0, accZ);
  MFG(1, accR);
  MFG(2, accX);

#undef MFG

  // -------- epilogue: gates in fp32, write h (f32 master + bf16) --------
#pragma unroll
  for (int nf = 0; nf < 2; ++nf) {
    int col = j0 + wn * 32 + nf * 16 + (lane & 15);
    float b_z = bias_i[col] + bias_r[col];
    float b_r = bias_i[H_DIM + col] + bias_r[H_DIM + col];
    float bih = bias_i[2 * H_DIM + col];
    float brh = bias_r[2 * H_DIM + col];
#pragma unroll
    for (int mf = 0; mf < 4; ++mf) {
#pragma unroll
      for (int q = 0; q < 4; ++q) {
        int row = r0 + wm * 64 + mf * 16 + (lane >> 4) * 4 + q;
        float z  = 1.f / (1.f + __expf(-(accZ[mf][nf][q] + b_z)));
        float rr = 1.f / (1.f + __expf(-(accR[mf][nf][q] + b_r)));
        float pre = accX[mf][nf][q] + bih + rr * (accH[mf][nf][q] + brh);
        float hc  = 2.f / (1.f + __expf(-2.f * pre)) - 1.f;   // tanh
        size_t idx = (size_t)row * H_DIM + col;
        float hold = hf[idx];
        float hnew = z * hold + (1.f - z) * hc;
        hf[idx] = hnew;
        hb_next[idx] = f2bf(hnew);
      }
    }
  }
}

// ---------------- final logits ----------------
__global__ __launch_bounds__(64) void logits_kernel(const float* __restrict__ hf,
                                                    const float* __restrict__ Wd,
                                                    const float* __restrict__ bd,
                                                    float* __restrict__ out) {
  int b = blockIdx.x;
  int l = threadIdx.x;
  float p[NLABEL];
#pragma unroll
  for (int o = 0; o < NLABEL; ++o) p[o] = 0.f;
  for (int kb = 0; kb < 16; ++kb) {
    int k = kb * 64 + l;
    float hv = hf[(size_t)b * H_DIM + k];
#pragma unroll
    for (int o = 0; o < NLABEL; ++o) p[o] += hv * Wd[k * NLABEL + o];
  }
#pragma unroll
  for (int o = 0; o < NLABEL; ++o) {
#pragma unroll
    for (int s = 32; s; s >>= 1) p[o] += __shfl_xor(p[o], s);
  }
  if (l == 0) {
#pragma unroll
    for (int o = 0; o < NLABEL; ++o) out[(size_t)b * NLABEL + o] = p[o] + bd[o];
  }
}

// ---------------- launch ----------------
extern "C" void kernel_launch(void* const* d_in, const int* in_sizes, int n_in,
                              void* d_out, int out_size, void* d_ws, size_t ws_size,
                              hipStream_t stream) {
  const int*   x          = (const int*)d_in[0];
  // d_in[1] = drop_rate (static 0, ignored)
  const float* emb_table  = (const float*)d_in[2];
  const float* kernel_w   = (const float*)d_in[3];
  const float* rec_kernel = (const float*)d_in[4];
  const float* bias_i     = (const float*)d_in[5];
  const float* bias_r     = (const float*)d_in[6];
  const float* Wd         = (const float*)d_in[7];
  const float* bd         = (const float*)d_in[8];
  float* out = (float*)d_out;

  char* ws = (char*)d_ws;
  size_t off = 0;
  auto alloc = [&](size_t bytes) {
    char* p = ws + off;
    off += (bytes + 255) & ~(size_t)255;
    return p;
  };
  float*    hf   = (float*)alloc((size_t)NB * H_DIM * 4);
  uint16_t* hb0  = (uint16_t*)alloc((size_t)NB * H_DIM * 2);
  uint16_t* hb1  = (uint16_t*)alloc((size_t)NB * H_DIM * 2);
  uint16_t* recT = (uint16_t*)alloc((size_t)G3 * H_DIM * 2);
  uint16_t* kerT = (uint16_t*)alloc((size_t)G3 * 64 * 2);
  uint16_t* embt = (uint16_t*)alloc((size_t)TSTEPS * NB * 64 * 2);
  uint16_t* Bpk  = (uint16_t*)alloc((size_t)16 * 17 * 12288 * 2);
  if (off > ws_size) return;  // insufficient workspace -> fail loudly

  hipMemsetAsync(hf, 0, (size_t)NB * H_DIM * 4, stream);
  hipMemsetAsync(hb0, 0, (size_t)NB * H_DIM * 2, stream);

  prep_recT<<<dim3(G3 / 64, H_DIM / 64), 256, 0, stream>>>(rec_kernel, recT);
  prep_kerT<<<G3 / 4, 256, 0, stream>>>(kernel_w, kerT);
  prep_pack<<<1632, 256, 0, stream>>>(recT, kerT, Bpk);
  prep_embt<<<TSTEPS * NB * 32 / 256, 256, 0, stream>>>(x, emb_table, embt);

  uint16_t* hb[2] = {hb0, hb1};
  for (int t = 0; t < TSTEPS; ++t) {
    gru_step_kernel<<<512, 256, 0, stream>>>(
        hb[t & 1], hf, hb[(t + 1) & 1], Bpk,
        embt + (size_t)t * NB * 64, bias_i, bias_r);
  }
  logits_kernel<<<NB, 64, 0, stream>>>(hf, Wd, bd, out);
}

// Round 15
// 3034.988 us; speedup vs baseline: 1.6425x; 1.0325x over previous
//
#include <hip/hip_runtime.h>
#include <stdint.h>

#define H_DIM   1024
#define G3      3072
#define EMB     50
#define TSTEPS  100
#define NB      4096
#define NLABEL  15

typedef __bf16 bf16x8 __attribute__((ext_vector_type(8)));
typedef float  f32x4  __attribute__((ext_vector_type(4)));
typedef int    i32x4  __attribute__((ext_vector_type(4)));

__device__ inline uint16_t f2bf(float f) {
  uint32_t u = __builtin_bit_cast(uint32_t, f);
  u += 0x7FFFu + ((u >> 16) & 1u);   // round-to-nearest-even
  return (uint16_t)(u >> 16);
}

__device__ inline void gld16(const void* g, void* l) {
  __builtin_amdgcn_global_load_lds(
      (const __attribute__((address_space(1))) uint32_t*)g,
      (__attribute__((address_space(3))) uint32_t*)l, 16, 0, 0);
}

// counted vmcnt + sched fence (rule #18: MFMA can hoist past bare asm waits)
#define VM(n) do { asm volatile("s_waitcnt vmcnt(" #n ")" ::: "memory"); \
                   __builtin_amdgcn_sched_barrier(0); } while (0)
#define LGKM0() do { asm volatile("s_waitcnt lgkmcnt(0)" ::: "memory"); \
                     __builtin_amdgcn_sched_barrier(0); } while (0)
#define BARF() do { __builtin_amdgcn_s_barrier(); \
                    asm volatile("" ::: "memory"); } while (0)

// ---------------- prep kernels (unchanged from r14) ----------------

__global__ __launch_bounds__(256) void prep_recT(const float* __restrict__ rec,
                                                 uint16_t* __restrict__ recT) {
  __shared__ uint16_t st[64][72];
  const int n0 = blockIdx.x * 64;
  const int k0 = blockIdx.y * 64;
  const int tid = threadIdx.x;
#pragma unroll
  for (int i = 0; i < 16; ++i) {
    int idx = tid + i * 256;
    int r = idx >> 6;
    int c = idx & 63;
    st[c][r] = f2bf(rec[(size_t)(k0 + r) * G3 + n0 + c]);
  }
  __syncthreads();
#pragma unroll
  for (int i = 0; i < 16; ++i) {
    int idx = tid + i * 256;
    int r = idx >> 6;
    int c = idx & 63;
    recT[(size_t)(n0 + r) * H_DIM + k0 + c] = st[r][c];
  }
}

__global__ __launch_bounds__(256) void prep_kerT(const float* __restrict__ ker,
                                                 uint16_t* __restrict__ kerT) {
  int n = blockIdx.x * 4 + (threadIdx.x >> 6);
  int k = threadIdx.x & 63;
  float v = (k < EMB) ? ker[(size_t)k * G3 + n] : 0.f;
  kerT[(size_t)n * 64 + k] = f2bf(v);
}

// Bpk[colblk16][kt17][g3][wn2][nf2][ks2][lane64][e8] bf16 — MFMA-fragment
// order. kt=16 = input-projection tile (from kerT). A block's tile slice is
// one contiguous 24576B region.
__global__ __launch_bounds__(256) void prep_pack(const uint16_t* __restrict__ recT,
                                                 const uint16_t* __restrict__ kerT,
                                                 uint16_t* __restrict__ Bpk) {
  int cid = blockIdx.x * 256 + threadIdx.x;   // 16B chunk id (417792 total)
  int lane = cid & 63;
  int r = cid >> 6;
  int ks = r & 1; r >>= 1;
  int nf = r & 1; r >>= 1;
  int wn = r & 1; r >>= 1;
  int g  = r % 3; r /= 3;
  int kt = r % 17;
  int colblk = r / 17;
  int n  = g * H_DIM + colblk * 64 + wn * 32 + nf * 16 + (lane & 15);
  int kk = ks * 32 + (lane >> 4) * 8;
  const uint16_t* src = (kt < 16) ? recT + (size_t)n * H_DIM + kt * 64 + kk
                                  : kerT + (size_t)n * 64 + kk;
  *reinterpret_cast<i32x4*>(Bpk + (size_t)cid * 8) =
      *reinterpret_cast<const i32x4*>(src);
}

__global__ __launch_bounds__(256) void prep_embt(const int* __restrict__ x,
                                                 const float* __restrict__ tab,
                                                 uint16_t* __restrict__ embt) {
  int idx = blockIdx.x * 256 + threadIdx.x;
  int g = idx >> 5;
  int p = idx & 31;
  int t = g >> 12;
  int b = g & 4095;
  int row = x[b * TSTEPS + t];
  float2 v;
  if (p < 25) v = *reinterpret_cast<const float2*>(tab + (size_t)row * EMB + 2 * p);
  else { v.x = 0.f; v.y = 0.f; }
  uint32_t packed = (uint32_t)f2bf(v.x) | ((uint32_t)f2bf(v.y) << 16);
  *reinterpret_cast<uint32_t*>(embt + (size_t)g * 64 + 2 * p) = packed;
}

// ---------------- fused GRU step ----------------
// grid 512 (2 blocks/CU), block 512 (8 waves, 2x4: each wave 64 rows x 16
// cols) -> 16 waves/CU = 4 waves/SIMD (2x the TLP of r14 at identical tile,
// LDS, schedule, and byte counts). B staged once per block into LDS (packed
// linear copy, double-buffered); A gld16->LDS XOR-swizzled. LDS = 80KB
// exactly. 2 barriers + one VM(5) per tile; vmcnt never 0 until the tail.
__global__ __launch_bounds__(512, 4) void gru_step_kernel(
    const uint16_t* __restrict__ hb_prev,   // [4096][1024] bf16
    float* __restrict__ hf,                 // [4096][1024] f32 (in-place)
    uint16_t* __restrict__ hb_next,         // [4096][1024] bf16
    const uint16_t* __restrict__ Bpk,       // packed B (see prep_pack)
    const uint16_t* __restrict__ embt,      // [4096][64]   bf16 (this step)
    const float* __restrict__ bias_i,       // [3072]
    const float* __restrict__ bias_r) {     // [3072]
  __shared__ __align__(16) uint16_t sA2[2][128 * 64];     // 32 KB
  __shared__ __align__(16) uint16_t sB2[2][12288];        // 48 KB

  const int tid  = threadIdx.x;
  const int lane = tid & 63;
  const int wid  = tid >> 6;     // 0..7
  const int wm   = wid >> 2;     // wave row 0..1 (64 rows each)
  const int wn   = wid & 3;      // wave col 0..3 (16 cols each)
  const int bid  = blockIdx.x;
  // XCD remap: xk = bid%8 -> XCD; each XCD: 8 rowblks x 8 colblks
  const int xk = bid & 7, slot = bid >> 3;          // slot 0..63
  const int rowblk = (xk >> 1) * 8 + (slot >> 3);   // 0..31
  const int colblk = (xk & 1) * 8 + (slot & 7);     // 0..15
  const int r0 = rowblk * 128;
  const int j0 = colblk * 64;

  const int swz8 = 8 * ((lane & 7) ^ (lane >> 3));

  const uint16_t* pBcol = Bpk + (size_t)colblk * 17 * 12288;

  bf16x8 af[4][2];               // A-frags: wave's 64 rows (single-buffered)
  bf16x8 bfr[3][2];              // B-frags [gate][ks] (single-buffered)
  f32x4 accZ[4], accR[4], accH[4], accX[4];
#pragma unroll
  for (int m = 0; m < 4; ++m) {
    accZ[m] = (f32x4){0.f, 0.f, 0.f, 0.f};
    accR[m] = (f32x4){0.f, 0.f, 0.f, 0.f};
    accH[m] = (f32x4){0.f, 0.f, 0.f, 0.f};
    accX[m] = (f32x4){0.f, 0.f, 0.f, 0.f};
  }

  // stage A-tile for tile t (2 gld16/thread, 16 KB)
  auto stageA = [&](int t) {
    const int abuf = t & 1;
#pragma unroll
    for (int i = 0; i < 2; ++i) {
      int chunk = wid * 2 + i;                // 0..15
      int row = chunk * 8 + (lane >> 3);
      const uint16_t* src = (t < 16)
          ? hb_prev + (size_t)(r0 + row) * H_DIM + t * 64 + swz8
          : embt + (size_t)(r0 + row) * 64 + swz8;
      gld16(src, &sA2[abuf][(chunk * 64 + lane) * 8]);
    }
  };
  // stage B-tile for tile t: linear copy of the packed 24576B region
  // (3 gld16/thread). LDS dest = wave-uniform base + lane*16 (linear). ✓
  auto stageB = [&](int t) {
    const int bbuf = t & 1;
    const uint16_t* base = pBcol + (size_t)t * 12288;
#pragma unroll
    for (int i = 0; i < 3; ++i) {
      int e = (i * 512 + tid) * 8;            // element offset
      gld16(base + e, &sB2[bbuf][e]);
    }
  };
  // read A fragments for tile t (8 ds_read_b128, swizzled)
  auto readA = [&](int t) {
    const int abuf = t & 1;
#pragma unroll
    for (int ks = 0; ks < 2; ++ks) {
      const int colswz = (ks * 32 + (lane >> 4) * 8) ^ ((lane & 7) << 3);
#pragma unroll
      for (int mf = 0; mf < 4; ++mf)
        af[mf][ks] = *reinterpret_cast<const bf16x8*>(
            &sA2[abuf][(wm * 64 + mf * 16 + (lane & 15)) * 64 + colswz]);
    }
  };
  // read B fragments for tile t (6 ds_read_b128, contiguous lane*16).
  // wave's 16-col slot wn -> packed chunk c = g*8 + wn*2 + ks
  // (since (wn>>1)*4 + (wn&1)*2 == wn*2 for wn in 0..3).
  auto readB = [&](int t) {
    const int bbuf = t & 1;
#pragma unroll
    for (int g = 0; g < 3; ++g)
#pragma unroll
      for (int ks = 0; ks < 2; ++ks) {
        int c = g * 8 + wn * 2 + ks;
        bfr[g][ks] = *reinterpret_cast<const bf16x8*>(
            &sB2[bbuf][c * 512 + lane * 8]);
      }
  };

// 8 MFMA of gate g into ACC (4 m-frags x 2 ks)
#define MFG(g, ACC) do { \
    __builtin_amdgcn_s_setprio(1); \
    _Pragma("unroll") for (int ks = 0; ks < 2; ++ks) \
    _Pragma("unroll") for (int mf = 0; mf < 4; ++mf) \
      ACC[mf] = __builtin_amdgcn_mfma_f32_16x16x32_bf16( \
          af[mf][ks], bfr[g][ks], ACC[mf], 0, 0, 0); \
    __builtin_amdgcn_s_setprio(0); \
  } while (0)

  // -------- prologue: stage tiles 0,1 (5 items each); read frags(0) --------
  stageA(0); stageB(0);
  stageA(1); stageB(1);
  VM(5);                         // S(0) landed; S(1) x5 in flight
  BARF();
  readA(0); readB(0);
  LGKM0();

  // -------- steady tiles 0..14 --------------------------------------------
  // invariant at loop top: frags(t) in regs; outstanding = [S(t+1) x5]
  for (int t = 0; t < 15; ++t) {
    BARF();                      // barrier-a: all threads done reading buf t%2
    stageA(t + 2); stageB(t + 2);        // overwrite buf t%2
    MFG(0, accZ);
    MFG(1, accR);
    MFG(2, accH);
    VM(5);                       // S(t+1) landed (mine); leave [S(t+2) x5]
    BARF();                      // barrier-b: S(t+1) landed for all
    readA(t + 1); readB(t + 1);  // frags for next tile
    LGKM0();
  }

  // -------- tile 15 (frags in regs; nothing to stage) ----------------------
  MFG(0, accZ);
  MFG(1, accR);
  MFG(2, accH);
  VM(0);                         // S(16) landed
  BARF();
  readA(16); readB(16);
  LGKM0();
  // -------- tile 16 (input projection; gate-2 -> accX) ---------------------
  MFG(0, accZ);
  MFG(1, accR);
  MFG(2, accX);

#undef MFG

  // -------- epilogue: gates in fp32, write h (f32 master + bf16) --------
  {
    const int col = j0 + wn * 16 + (lane & 15);
    const float b_z = bias_i[col] + bias_r[col];
    const float b_r = bias_i[H_DIM + col] + bias_r[H_DIM + col];
    const float bih = bias_i[2 * H_DIM + col];
    const float brh = bias_r[2 * H_DIM + col];
#pragma unroll
    for (int mf = 0; mf < 4; ++mf) {
#pragma unroll
      for (int q = 0; q < 4; ++q) {
        int row = r0 + wm * 64 + mf * 16 + (lane >> 4) * 4 + q;
        float z  = 1.f / (1.f + __expf(-(accZ[mf][q] + b_z)));
        float rr = 1.f / (1.f + __expf(-(accR[mf][q] + b_r)));
        float pre = accX[mf][q] + bih + rr * (accH[mf][q] + brh);
        float hc  = 2.f / (1.f + __expf(-2.f * pre)) - 1.f;   // tanh
        size_t idx = (size_t)row * H_DIM + col;
        float hold = hf[idx];
        float hnew = z * hold + (1.f - z) * hc;
        hf[idx] = hnew;
        hb_next[idx] = f2bf(hnew);
      }
    }
  }
}

// ---------------- final logits ----------------
__global__ __launch_bounds__(64) void logits_kernel(const float* __restrict__ hf,
                                                    const float* __restrict__ Wd,
                                                    const float* __restrict__ bd,
                                                    float* __restrict__ out) {
  int b = blockIdx.x;
  int l = threadIdx.x;
  float p[NLABEL];
#pragma unroll
  for (int o = 0; o < NLABEL; ++o) p[o] = 0.f;
  for (int kb = 0; kb < 16; ++kb) {
    int k = kb * 64 + l;
    float hv = hf[(size_t)b * H_DIM + k];
#pragma unroll
    for (int o = 0; o < NLABEL; ++o) p[o] += hv * Wd[k * NLABEL + o];
  }
#pragma unroll
  for (int o = 0; o < NLABEL; ++o) {
#pragma unroll
    for (int s = 32; s; s >>= 1) p[o] += __shfl_xor(p[o], s);
  }
  if (l == 0) {
#pragma unroll
    for (int o = 0; o < NLABEL; ++o) out[(size_t)b * NLABEL + o] = p[o] + bd[o];
  }
}

// ---------------- launch ----------------
extern "C" void kernel_launch(void* const* d_in, const int* in_sizes, int n_in,
                              void* d_out, int out_size, void* d_ws, size_t ws_size,
                              hipStream_t stream) {
  const int*   x          = (const int*)d_in[0];
  // d_in[1] = drop_rate (static 0, ignored)
  const float* emb_table  = (const float*)d_in[2];
  const float* kernel_w   = (const float*)d_in[3];
  const float* rec_kernel = (const float*)d_in[4];
  const float* bias_i     = (const float*)d_in[5];
  const float* bias_r     = (const float*)d_in[6];
  const float* Wd         = (const float*)d_in[7];
  const float* bd         = (const float*)d_in[8];
  float* out = (float*)d_out;

  char* ws = (char*)d_ws;
  size_t off = 0;
  auto alloc = [&](size_t bytes) {
    char* p = ws + off;
    off += (bytes + 255) & ~(size_t)255;
    return p;
  };
  float*    hf   = (float*)alloc((size_t)NB * H_DIM * 4);
  uint16_t* hb0  = (uint16_t*)alloc((size_t)NB * H_DIM * 2);
  uint16_t* hb1  = (uint16_t*)alloc((size_t)NB * H_DIM * 2);
  uint16_t* recT = (uint16_t*)alloc((size_t)G3 * H_DIM * 2);
  uint16_t* kerT = (uint16_t*)alloc((size_t)G3 * 64 * 2);
  uint16_t* embt = (uint16_t*)alloc((size_t)TSTEPS * NB * 64 * 2);
  uint16_t* Bpk  = (uint16_t*)alloc((size_t)16 * 17 * 12288 * 2);
  if (off > ws_size) return;  // insufficient workspace -> fail loudly

  hipMemsetAsync(hf, 0, (size_t)NB * H_DIM * 4, stream);
  hipMemsetAsync(hb0, 0, (size_t)NB * H_DIM * 2, stream);

  prep_recT<<<dim3(G3 / 64, H_DIM / 64), 256, 0, stream>>>(rec_kernel, recT);
  prep_kerT<<<G3 / 4, 256, 0, stream>>>(kernel_w, kerT);
  prep_pack<<<1632, 256, 0, stream>>>(recT, kerT, Bpk);
  prep_embt<<<TSTEPS * NB * 32 / 256, 256, 0, stream>>>(x, emb_table, embt);

  uint16_t* hb[2] = {hb0, hb1};
  for (int t = 0; t < TSTEPS; ++t) {
    gru_step_kernel<<<512, 512, 0, stream>>>(
        hb[t & 1], hf, hb[(t + 1) & 1], Bpk,
        embt + (size_t)t * NB * 64, bias_i, bias_r);
  }
  logits_kernel<<<NB, 64, 0, stream>>>(hf, Wd, bd, out);
}